// Round 2
// baseline (517.206 us; speedup 1.0000x reference)
//
#include <hip/hip_runtime.h>

#define NNODES 8192
#define NEDGES 262144
#define FIN 512
#define FHID 512
#define FLAT 128

typedef unsigned short bfu;   // raw bf16 bits
typedef __attribute__((ext_vector_type(8))) short short8;
typedef __attribute__((ext_vector_type(4))) float f32x4;

__device__ __forceinline__ float bf2f(unsigned short u) {
    union { unsigned int i; float f; } c; c.i = ((unsigned int)u) << 16; return c.f;
}
__device__ __forceinline__ unsigned short f2bf(float f) {
    union { float f; unsigned int i; } c; c.f = f;
    unsigned int i = c.i;
    unsigned int r = (i + 0x7FFFu + ((i >> 16) & 1u)) >> 16;  // RNE
    return (unsigned short)r;
}

// ---------- graph preprocessing ----------
__global__ void k_zero(int* p, int n) {
    int i = blockIdx.x * blockDim.x + threadIdx.x;
    if (i < n) p[i] = 0;
}

__global__ void k_count(const int* __restrict__ ei, int* __restrict__ deg) {
    int e = blockIdx.x * blockDim.x + threadIdx.x;
    if (e < NEDGES) atomicAdd(&deg[ei[NEDGES + e]], 1);
}

// single block, 256 threads: exclusive scan of deg -> row_start, plus dinv = rsqrt(deg+1)
__global__ void k_scan(const int* __restrict__ deg, int* __restrict__ row_start,
                       float* __restrict__ dinv) {
    __shared__ int part[256];
    int t = threadIdx.x, base = t * 32;
    int s = 0;
    for (int i = 0; i < 32; i++) s += deg[base + i];
    part[t] = s;
    __syncthreads();
    for (int off = 1; off < 256; off <<= 1) {
        int v = (t >= off) ? part[t - off] : 0;
        __syncthreads();
        part[t] += v;
        __syncthreads();
    }
    int run = (t == 0) ? 0 : part[t - 1];
    for (int i = 0; i < 32; i++) {
        int d = deg[base + i];
        row_start[base + i] = run;
        run += d;
        dinv[base + i] = rsqrtf((float)(d + 1));  // +1 self-loop
    }
    if (t == 255) row_start[NNODES] = run;
}

__global__ void k_scatter(const int* __restrict__ ei, const int* __restrict__ row_start,
                          int* __restrict__ cursor, int* __restrict__ csr) {
    int e = blockIdx.x * blockDim.x + threadIdx.x;
    if (e < NEDGES) {
        int dst = ei[NEDGES + e];
        int p = atomicAdd(&cursor[dst], 1);
        csr[row_start[dst] + p] = ei[e];  // src node
    }
}

// ---------- x (fp32) -> bf16 ----------
__global__ void k_cvt_x(const float* __restrict__ x, bfu* __restrict__ xb) {
    int i = blockIdx.x * blockDim.x + threadIdx.x;  // over float4s
    const float4 v = ((const float4*)x)[i];
    ushort2 lo = {f2bf(v.x), f2bf(v.y)};
    ushort2 hi = {f2bf(v.z), f2bf(v.w)};
    ((ushort2*)xb)[2 * i] = lo;
    ((ushort2*)xb)[2 * i + 1] = hi;
}

// ---------- weight transposes (fp32 -> bf16): Bt[n*K+k] = W[k*N+n]; Bt2 = [Wmu|Wlv]^T ----------
__global__ void k_bt(const float* __restrict__ W1, const float* __restrict__ Wmu,
                     const float* __restrict__ Wlv, bfu* __restrict__ Bt1, bfu* __restrict__ Bt2) {
    int idx = blockIdx.x * blockDim.x + threadIdx.x;
    if (idx < 512 * 512) {
        int n = idx >> 9, k = idx & 511;
        Bt1[idx] = f2bf(W1[k * 512 + n]);
    } else if (idx < 512 * 512 + 256 * 512) {
        int j = idx - 512 * 512;
        int n = j >> 9, k = j & 511;
        Bt2[j] = f2bf((n < 128) ? Wmu[k * 128 + n] : Wlv[k * 128 + (n - 128)]);
    }
}

// ---------- generic NT GEMM: C[M,N] = act(A[M,K] @ Bt[N,K]^T), bf16 in, fp32 acc ----------
// wave computes a 64x64 tile via 4x4 grid of 16x16x32 MFMAs
// ACT: 0 = none (bf16 C), 2 = sigmoid (fp32 C)
template <int ACT, typename CT>
__global__ void k_gemm_nt(const bfu* __restrict__ A, const bfu* __restrict__ Bt,
                          CT* __restrict__ C, int M, int N, int K) {
    int wid  = (blockIdx.x * blockDim.x + threadIdx.x) >> 6;
    int lane = threadIdx.x & 63;
    int l = lane & 15, q = lane >> 4;
    int tn = N >> 6;
    int m0 = (wid / tn) << 6, n0 = (wid % tn) << 6;

    f32x4 acc[4][4];
#pragma unroll
    for (int a = 0; a < 4; a++)
#pragma unroll
        for (int b = 0; b < 4; b++) acc[a][b] = (f32x4){0.f, 0.f, 0.f, 0.f};

    const bfu* Ap = A + (size_t)(m0 + l) * K + q * 8;
    const bfu* Bp = Bt + (size_t)(n0 + l) * K + q * 8;

    for (int k0 = 0; k0 < K; k0 += 32) {
        short8 av[4], bv[4];
#pragma unroll
        for (int mi = 0; mi < 4; mi++)
            av[mi] = *(const short8*)(Ap + (size_t)mi * 16 * K + k0);
#pragma unroll
        for (int ni = 0; ni < 4; ni++)
            bv[ni] = *(const short8*)(Bp + (size_t)ni * 16 * K + k0);
#pragma unroll
        for (int mi = 0; mi < 4; mi++)
#pragma unroll
            for (int ni = 0; ni < 4; ni++)
                acc[mi][ni] = __builtin_amdgcn_mfma_f32_16x16x32_bf16(av[mi], bv[ni],
                                                                     acc[mi][ni], 0, 0, 0);
    }

#pragma unroll
    for (int mi = 0; mi < 4; mi++)
#pragma unroll
        for (int ni = 0; ni < 4; ni++) {
            int col = n0 + ni * 16 + l;
#pragma unroll
            for (int r = 0; r < 4; r++) {
                int row = m0 + mi * 16 + q * 4 + r;
                float v = acc[mi][ni][r];
                if (ACT == 2) v = 1.0f / (1.0f + __expf(-v));
                if constexpr (sizeof(CT) == 2)
                    C[(size_t)row * N + col] = (CT)f2bf(v);
                else
                    C[(size_t)row * N + col] = (CT)v;
            }
        }
}

// ---------- aggregation layer 1: h = relu(D^-1/2 A D^-1/2 h0 + b1), F=512, bf16 in/out ----------
__global__ void k_agg1(const bfu* __restrict__ hin, const int* __restrict__ csr,
                       const int* __restrict__ rs, const float* __restrict__ dinv,
                       const float* __restrict__ bias, bfu* __restrict__ hout) {
    int i = blockIdx.x;
    int f = threadIdx.x * 2;  // 256 threads x 2 features
    float a0 = 0.f, a1 = 0.f;
    int s = rs[i], e = rs[i + 1];
    for (int ed = s; ed < e; ed++) {
        int src = csr[ed];
        float w = dinv[src];
        unsigned int pk = *(const unsigned int*)(hin + (size_t)src * FHID + f);
        a0 += w * bf2f((unsigned short)(pk & 0xFFFF));
        a1 += w * bf2f((unsigned short)(pk >> 16));
    }
    float di = dinv[i];
    unsigned int pk = *(const unsigned int*)(hin + (size_t)i * FHID + f);
    a0 += di * bf2f((unsigned short)(pk & 0xFFFF));
    a1 += di * bf2f((unsigned short)(pk >> 16));
    float o0 = fmaxf(di * a0 + bias[f], 0.f);
    float o1 = fmaxf(di * a1 + bias[f + 1], 0.f);
    unsigned int outw = (unsigned int)f2bf(o0) | ((unsigned int)f2bf(o1) << 16);
    *(unsigned int*)(hout + (size_t)i * FHID + f) = outw;
}

// ---------- aggregation layer 2/3 fused: F=256 ([mu | logvar]); fp32 mu/lv/z + bf16 z ----------
__global__ void k_agg2(const bfu* __restrict__ hin, const int* __restrict__ csr,
                       const int* __restrict__ rs, const float* __restrict__ dinv,
                       const float* __restrict__ bmu, const float* __restrict__ blv,
                       float* __restrict__ out_mu, float* __restrict__ out_lv,
                       float* __restrict__ out_z, bfu* __restrict__ ws_z) {
    int i = blockIdx.x;
    int f = threadIdx.x * 2;  // 128 threads x 2 features over 256
    float a0 = 0.f, a1 = 0.f;
    int s = rs[i], e = rs[i + 1];
    for (int ed = s; ed < e; ed++) {
        int src = csr[ed];
        float w = dinv[src];
        unsigned int pk = *(const unsigned int*)(hin + (size_t)src * 256 + f);
        a0 += w * bf2f((unsigned short)(pk & 0xFFFF));
        a1 += w * bf2f((unsigned short)(pk >> 16));
    }
    float di = dinv[i];
    unsigned int pk = *(const unsigned int*)(hin + (size_t)i * 256 + f);
    a0 += di * bf2f((unsigned short)(pk & 0xFFFF));
    a1 += di * bf2f((unsigned short)(pk >> 16));
    float v0 = di * a0, v1 = di * a1;
    if (f < 128) {
        v0 += bmu[f]; v1 += bmu[f + 1];
        float2 fv = {v0, v1};
        *(float2*)(out_mu + (size_t)i * FLAT + f) = fv;
        *(float2*)(out_z + (size_t)i * FLAT + f) = fv;   // z = mu (eval mode)
        unsigned int bw = (unsigned int)f2bf(v0) | ((unsigned int)f2bf(v1) << 16);
        *(unsigned int*)(ws_z + (size_t)i * FLAT + f) = bw;
    } else {
        int fl = f - 128;
        v0 += blv[fl]; v1 += blv[fl + 1];
        float2 fv = {v0, v1};
        *(float2*)(out_lv + (size_t)i * FLAT + fl) = fv;
    }
}

extern "C" void kernel_launch(void* const* d_in, const int* in_sizes, int n_in,
                              void* d_out, int out_size, void* d_ws, size_t ws_size,
                              hipStream_t stream) {
    const int*   ei  = (const int*)d_in[0];
    const float* x   = (const float*)d_in[1];
    const float* W1  = (const float*)d_in[2];
    const float* b1  = (const float*)d_in[3];
    const float* Wmu = (const float*)d_in[4];
    const float* bmu = (const float*)d_in[5];
    const float* Wlv = (const float*)d_in[6];
    const float* blv = (const float*)d_in[7];
    float* out = (float*)d_out;

    char* wsb = (char*)d_ws;
    size_t off = 0;
    auto alloc = [&](size_t bytes) -> char* {
        char* p = wsb + off;
        off += (bytes + 255) & ~(size_t)255;
        return p;
    };
    int*   deg       = (int*)alloc(NNODES * 4);
    int*   cursor    = (int*)alloc(NNODES * 4);   // contiguous after deg
    int*   row_start = (int*)alloc((NNODES + 1) * 4);
    float* dinv      = (float*)alloc(NNODES * 4);
    int*   csr       = (int*)alloc(NEDGES * 4);
    bfu*   Bt1       = (bfu*)alloc(512 * 512 * 2);
    bfu*   Bt2       = (bfu*)alloc(256 * 512 * 2);
    bfu*   xb        = (bfu*)alloc((size_t)NNODES * FIN * 2);
    bfu*   h0        = (bfu*)alloc((size_t)NNODES * FHID * 2);
    bfu*   h         = (bfu*)alloc((size_t)NNODES * FHID * 2);
    bfu*   hml       = (bfu*)alloc((size_t)NNODES * 256 * 2);
    bfu*   zb        = (bfu*)alloc((size_t)NNODES * FLAT * 2);

    float* out_mu = out + (size_t)NNODES * NNODES;
    float* out_lv = out_mu + (size_t)NNODES * FLAT;
    float* out_z  = out_lv + (size_t)NNODES * FLAT;

    // graph prep
    k_zero<<<(2 * NNODES + 255) / 256, 256, 0, stream>>>(deg, 2 * NNODES);  // deg + cursor
    k_count<<<NEDGES / 256, 256, 0, stream>>>(ei, deg);
    k_scan<<<1, 256, 0, stream>>>(deg, row_start, dinv);
    k_scatter<<<NEDGES / 256, 256, 0, stream>>>(ei, row_start, cursor, csr);
    k_bt<<<(512 * 512 + 256 * 512) / 256, 256, 0, stream>>>(W1, Wmu, Wlv, Bt1, Bt2);
    k_cvt_x<<<(NNODES * FIN / 4) / 256, 256, 0, stream>>>(x, xb);

    // layer 1: h0 = x @ W1 ; h = relu(agg(h0) + b1)
    k_gemm_nt<0, bfu><<<(8192 / 64) * (512 / 64) / 4, 256, 0, stream>>>(xb, Bt1, h0, 8192, 512, 512);
    k_agg1<<<NNODES, 256, 0, stream>>>(h0, csr, row_start, dinv, b1, h);

    // layers 2+3 fused: hml = h @ [Wmu|Wlv] ; mu/lv = agg(hml) + b ; z = mu
    k_gemm_nt<0, bfu><<<(8192 / 64) * (256 / 64) / 4, 256, 0, stream>>>(h, Bt2, hml, 8192, 256, 512);
    k_agg2<<<NNODES, 128, 0, stream>>>(hml, csr, row_start, dinv, bmu, blv,
                                       out_mu, out_lv, out_z, zb);

    // decode: A_pred = sigmoid(z @ z^T), fp32 out
    k_gemm_nt<2, float><<<(8192 / 64) * (8192 / 64) / 4, 256, 0, stream>>>(zb, zb, out, 8192, 8192, 128);
}

// Round 3
// 478.477 us; speedup vs baseline: 1.0809x; 1.0809x over previous
//
#include <hip/hip_runtime.h>

#define NNODES 8192
#define NEDGES 262144
#define FIN 512
#define FHID 512
#define FLAT 128

typedef unsigned short bfu;   // raw bf16 bits
typedef __attribute__((ext_vector_type(8))) short short8;
typedef __attribute__((ext_vector_type(4))) float f32x4;
typedef __attribute__((ext_vector_type(4))) unsigned short us4;

__device__ __forceinline__ float bf2f(unsigned short u) {
    union { unsigned int i; float f; } c; c.i = ((unsigned int)u) << 16; return c.f;
}
__device__ __forceinline__ unsigned short f2bf(float f) {
    union { float f; unsigned int i; } c; c.f = f;
    unsigned int i = c.i;
    unsigned int r = (i + 0x7FFFu + ((i >> 16) & 1u)) >> 16;  // RNE
    return (unsigned short)r;
}

// ---------- graph preprocessing ----------
__global__ void k_zero(int* p, int n) {
    int i = blockIdx.x * blockDim.x + threadIdx.x;
    if (i < n) p[i] = 0;
}

__global__ void k_count(const int* __restrict__ ei, int* __restrict__ deg) {
    int e = blockIdx.x * blockDim.x + threadIdx.x;
    if (e < NEDGES) atomicAdd(&deg[ei[NEDGES + e]], 1);
}

// single block, 256 threads: exclusive scan of deg -> row_start, plus dinv = rsqrt(deg+1)
__global__ void k_scan(const int* __restrict__ deg, int* __restrict__ row_start,
                       float* __restrict__ dinv) {
    __shared__ int part[256];
    int t = threadIdx.x, base = t * 32;
    int s = 0;
    for (int i = 0; i < 32; i++) s += deg[base + i];
    part[t] = s;
    __syncthreads();
    for (int off = 1; off < 256; off <<= 1) {
        int v = (t >= off) ? part[t - off] : 0;
        __syncthreads();
        part[t] += v;
        __syncthreads();
    }
    int run = (t == 0) ? 0 : part[t - 1];
    for (int i = 0; i < 32; i++) {
        int d = deg[base + i];
        row_start[base + i] = run;
        run += d;
        dinv[base + i] = rsqrtf((float)(d + 1));  // +1 self-loop
    }
    if (t == 255) row_start[NNODES] = run;
}

__global__ void k_scatter(const int* __restrict__ ei, const int* __restrict__ row_start,
                          int* __restrict__ cursor, int* __restrict__ csr) {
    int e = blockIdx.x * blockDim.x + threadIdx.x;
    if (e < NEDGES) {
        int dst = ei[NEDGES + e];
        int p = atomicAdd(&cursor[dst], 1);
        csr[row_start[dst] + p] = ei[e];  // src node
    }
}

// per-edge source weight (streaming) so the agg loop avoids a dependent dinv gather
__global__ void k_wcsr(const int* __restrict__ csr, const float* __restrict__ dinv,
                       float* __restrict__ wcsr) {
    int p = blockIdx.x * blockDim.x + threadIdx.x;
    if (p < NEDGES) wcsr[p] = dinv[csr[p]];
}

// ---------- x (fp32) -> bf16 ----------
__global__ void k_cvt_x(const float* __restrict__ x, bfu* __restrict__ xb) {
    int i = blockIdx.x * blockDim.x + threadIdx.x;  // over float4s
    const float4 v = ((const float4*)x)[i];
    ushort2 lo = {f2bf(v.x), f2bf(v.y)};
    ushort2 hi = {f2bf(v.z), f2bf(v.w)};
    ((ushort2*)xb)[2 * i] = lo;
    ((ushort2*)xb)[2 * i + 1] = hi;
}

// ---------- weight transposes (fp32 -> bf16): Bt[n*K+k] = W[k*N+n]; Bt2 = [Wmu|Wlv]^T ----------
__global__ void k_bt(const float* __restrict__ W1, const float* __restrict__ Wmu,
                     const float* __restrict__ Wlv, bfu* __restrict__ Bt1, bfu* __restrict__ Bt2) {
    int idx = blockIdx.x * blockDim.x + threadIdx.x;
    if (idx < 512 * 512) {
        int n = idx >> 9, k = idx & 511;
        Bt1[idx] = f2bf(W1[k * 512 + n]);
    } else if (idx < 512 * 512 + 256 * 512) {
        int j = idx - 512 * 512;
        int n = j >> 9, k = j & 511;
        Bt2[j] = f2bf((n < 128) ? Wmu[k * 128 + n] : Wlv[k * 128 + (n - 128)]);
    }
}

// ---------- generic NT GEMM: C[M,N] = act(A[M,K] @ Bt[N,K]^T), bf16 in, fp32 acc ----------
// wave computes a (16*TM)x(16*TN) tile. Operand-swapped MFMA so acc f32x4 maps to 4
// consecutive output columns -> vector stores (float4 / us4).
// ACT: 0 = none, 2 = sigmoid
template <int ACT, int TM, int TN, typename CT>
__global__ void k_gemm_nt(const bfu* __restrict__ A, const bfu* __restrict__ Bt,
                          CT* __restrict__ C, int M, int N, int K) {
    int wid  = (blockIdx.x * blockDim.x + threadIdx.x) >> 6;
    int lane = threadIdx.x & 63;
    int l = lane & 15, q = lane >> 4;
    int tn = N / (16 * TN);
    int m0 = (wid / tn) * (16 * TM), n0 = (wid % tn) * (16 * TN);

    f32x4 acc[TM][TN];
#pragma unroll
    for (int a = 0; a < TM; a++)
#pragma unroll
        for (int b = 0; b < TN; b++) acc[a][b] = (f32x4){0.f, 0.f, 0.f, 0.f};

    const bfu* Ap = A + (size_t)(m0 + l) * K + q * 8;
    const bfu* Bp = Bt + (size_t)(n0 + l) * K + q * 8;

    for (int k0 = 0; k0 < K; k0 += 32) {
        short8 av[TM], bv[TN];
#pragma unroll
        for (int mi = 0; mi < TM; mi++)
            av[mi] = *(const short8*)(Ap + (size_t)mi * 16 * K + k0);
#pragma unroll
        for (int ni = 0; ni < TN; ni++)
            bv[ni] = *(const short8*)(Bp + (size_t)ni * 16 * K + k0);
#pragma unroll
        for (int mi = 0; mi < TM; mi++)
#pragma unroll
            for (int ni = 0; ni < TN; ni++)
                acc[mi][ni] = __builtin_amdgcn_mfma_f32_16x16x32_bf16(bv[ni], av[mi],
                                                                     acc[mi][ni], 0, 0, 0);
    }

    // operand-swapped C layout: value acc[mi][ni][r] = C[m0+mi*16+l][n0+ni*16+q*4+r]
#pragma unroll
    for (int mi = 0; mi < TM; mi++) {
        int row = m0 + mi * 16 + l;
#pragma unroll
        for (int ni = 0; ni < TN; ni++) {
            int col = n0 + ni * 16 + q * 4;
            f32x4 v = acc[mi][ni];
            if (ACT == 2) {
#pragma unroll
                for (int r = 0; r < 4; r++)
                    v[r] = __builtin_amdgcn_rcpf(1.0f + __expf(-v[r]));
            }
            if constexpr (sizeof(CT) == 2) {
                us4 o = {f2bf(v[0]), f2bf(v[1]), f2bf(v[2]), f2bf(v[3])};
                *(us4*)(C + (size_t)row * N + col) = o;
            } else {
                *(f32x4*)(C + (size_t)row * N + col) = v;
            }
        }
    }
}

// ---------- aggregation, F features, edge loop batched x4 ----------
// out = di * (sum_j w_j * hin[src_j] + di * hin[i])  (self-loop folded in)
template <int F>
__device__ __forceinline__ void agg_core(const bfu* __restrict__ hin,
                                         const int* __restrict__ csr,
                                         const float* __restrict__ wcsr,
                                         int s, int e, int i, int f, float di,
                                         float& a0, float& a1) {
    a0 = 0.f; a1 = 0.f;
    int ed = s;
    for (; ed + 4 <= e; ed += 4) {
        int s0 = csr[ed], s1 = csr[ed + 1], s2 = csr[ed + 2], s3 = csr[ed + 3];
        float w0 = wcsr[ed], w1 = wcsr[ed + 1], w2 = wcsr[ed + 2], w3 = wcsr[ed + 3];
        unsigned int p0 = *(const unsigned int*)(hin + (size_t)s0 * F + f);
        unsigned int p1 = *(const unsigned int*)(hin + (size_t)s1 * F + f);
        unsigned int p2 = *(const unsigned int*)(hin + (size_t)s2 * F + f);
        unsigned int p3 = *(const unsigned int*)(hin + (size_t)s3 * F + f);
        a0 += w0 * bf2f((unsigned short)(p0 & 0xFFFF));
        a1 += w0 * bf2f((unsigned short)(p0 >> 16));
        a0 += w1 * bf2f((unsigned short)(p1 & 0xFFFF));
        a1 += w1 * bf2f((unsigned short)(p1 >> 16));
        a0 += w2 * bf2f((unsigned short)(p2 & 0xFFFF));
        a1 += w2 * bf2f((unsigned short)(p2 >> 16));
        a0 += w3 * bf2f((unsigned short)(p3 & 0xFFFF));
        a1 += w3 * bf2f((unsigned short)(p3 >> 16));
    }
    for (; ed < e; ed++) {
        int src = csr[ed];
        float w = wcsr[ed];
        unsigned int pk = *(const unsigned int*)(hin + (size_t)src * F + f);
        a0 += w * bf2f((unsigned short)(pk & 0xFFFF));
        a1 += w * bf2f((unsigned short)(pk >> 16));
    }
    unsigned int pk = *(const unsigned int*)(hin + (size_t)i * F + f);
    a0 += di * bf2f((unsigned short)(pk & 0xFFFF));
    a1 += di * bf2f((unsigned short)(pk >> 16));
}

// layer 1: h = relu(D^-1/2 A D^-1/2 h0 + b1), F=512, bf16 in/out
__global__ void k_agg1(const bfu* __restrict__ hin, const int* __restrict__ csr,
                       const float* __restrict__ wcsr, const int* __restrict__ rs,
                       const float* __restrict__ dinv, const float* __restrict__ bias,
                       bfu* __restrict__ hout) {
    int i = blockIdx.x;
    int f = threadIdx.x * 2;  // 256 threads x 2 features
    float di = dinv[i];
    float a0, a1;
    agg_core<FHID>(hin, csr, wcsr, rs[i], rs[i + 1], i, f, di, a0, a1);
    float o0 = fmaxf(di * a0 + bias[f], 0.f);
    float o1 = fmaxf(di * a1 + bias[f + 1], 0.f);
    unsigned int outw = (unsigned int)f2bf(o0) | ((unsigned int)f2bf(o1) << 16);
    *(unsigned int*)(hout + (size_t)i * FHID + f) = outw;
}

// layers 2/3 fused: F=256 ([mu | logvar]); fp32 mu/lv/z + bf16 z
__global__ void k_agg2(const bfu* __restrict__ hin, const int* __restrict__ csr,
                       const float* __restrict__ wcsr, const int* __restrict__ rs,
                       const float* __restrict__ dinv, const float* __restrict__ bmu,
                       const float* __restrict__ blv, float* __restrict__ out_mu,
                       float* __restrict__ out_lv, float* __restrict__ out_z,
                       bfu* __restrict__ ws_z) {
    int i = blockIdx.x;
    int f = threadIdx.x * 2;  // 128 threads x 2 features over 256
    float di = dinv[i];
    float a0, a1;
    agg_core<256>(hin, csr, wcsr, rs[i], rs[i + 1], i, f, di, a0, a1);
    float v0 = di * a0, v1 = di * a1;
    if (f < 128) {
        v0 += bmu[f]; v1 += bmu[f + 1];
        float2 fv = {v0, v1};
        *(float2*)(out_mu + (size_t)i * FLAT + f) = fv;
        *(float2*)(out_z + (size_t)i * FLAT + f) = fv;   // z = mu (eval mode)
        unsigned int bw = (unsigned int)f2bf(v0) | ((unsigned int)f2bf(v1) << 16);
        *(unsigned int*)(ws_z + (size_t)i * FLAT + f) = bw;
    } else {
        int fl = f - 128;
        v0 += blv[fl]; v1 += blv[fl + 1];
        float2 fv = {v0, v1};
        *(float2*)(out_lv + (size_t)i * FLAT + fl) = fv;
    }
}

extern "C" void kernel_launch(void* const* d_in, const int* in_sizes, int n_in,
                              void* d_out, int out_size, void* d_ws, size_t ws_size,
                              hipStream_t stream) {
    const int*   ei  = (const int*)d_in[0];
    const float* x   = (const float*)d_in[1];
    const float* W1  = (const float*)d_in[2];
    const float* b1  = (const float*)d_in[3];
    const float* Wmu = (const float*)d_in[4];
    const float* bmu = (const float*)d_in[5];
    const float* Wlv = (const float*)d_in[6];
    const float* blv = (const float*)d_in[7];
    float* out = (float*)d_out;

    char* wsb = (char*)d_ws;
    size_t off = 0;
    auto alloc = [&](size_t bytes) -> char* {
        char* p = wsb + off;
        off += (bytes + 255) & ~(size_t)255;
        return p;
    };
    int*   deg       = (int*)alloc(NNODES * 4);
    int*   cursor    = (int*)alloc(NNODES * 4);   // contiguous after deg
    int*   row_start = (int*)alloc((NNODES + 1) * 4);
    float* dinv      = (float*)alloc(NNODES * 4);
    int*   csr       = (int*)alloc(NEDGES * 4);
    float* wcsr      = (float*)alloc(NEDGES * 4);
    bfu*   Bt1       = (bfu*)alloc(512 * 512 * 2);
    bfu*   Bt2       = (bfu*)alloc(256 * 512 * 2);
    bfu*   xb        = (bfu*)alloc((size_t)NNODES * FIN * 2);
    bfu*   h0        = (bfu*)alloc((size_t)NNODES * FHID * 2);
    bfu*   h         = (bfu*)alloc((size_t)NNODES * FHID * 2);
    bfu*   hml       = (bfu*)alloc((size_t)NNODES * 256 * 2);
    bfu*   zb        = (bfu*)alloc((size_t)NNODES * FLAT * 2);

    float* out_mu = out + (size_t)NNODES * NNODES;
    float* out_lv = out_mu + (size_t)NNODES * FLAT;
    float* out_z  = out_lv + (size_t)NNODES * FLAT;

    // graph prep
    k_zero<<<(2 * NNODES + 255) / 256, 256, 0, stream>>>(deg, 2 * NNODES);  // deg + cursor
    k_count<<<NEDGES / 256, 256, 0, stream>>>(ei, deg);
    k_scan<<<1, 256, 0, stream>>>(deg, row_start, dinv);
    k_scatter<<<NEDGES / 256, 256, 0, stream>>>(ei, row_start, cursor, csr);
    k_wcsr<<<NEDGES / 256, 256, 0, stream>>>(csr, dinv, wcsr);
    k_bt<<<(512 * 512 + 256 * 512) / 256, 256, 0, stream>>>(W1, Wmu, Wlv, Bt1, Bt2);
    k_cvt_x<<<(NNODES * FIN / 4) / 256, 256, 0, stream>>>(x, xb);

    // layer 1: h0 = x @ W1 (64x32/wave -> 2048 waves) ; h = relu(agg(h0) + b1)
    k_gemm_nt<0, 4, 2, bfu><<<(8192 / 64) * (512 / 32) / 4, 256, 0, stream>>>(
        xb, Bt1, h0, 8192, 512, 512);
    k_agg1<<<NNODES, 256, 0, stream>>>(h0, csr, wcsr, row_start, dinv, b1, h);

    // layers 2+3 fused: hml = h @ [Wmu|Wlv] (32x32/wave -> 2048 waves)
    k_gemm_nt<0, 2, 2, bfu><<<(8192 / 32) * (256 / 32) / 4, 256, 0, stream>>>(
        h, Bt2, hml, 8192, 256, 512);
    k_agg2<<<NNODES, 128, 0, stream>>>(hml, csr, wcsr, row_start, dinv, bmu, blv,
                                       out_mu, out_lv, out_z, zb);

    // decode: A_pred = sigmoid(z @ z^T), fp32 out, 64x64/wave -> 16384 waves
    k_gemm_nt<2, 4, 4, float><<<(8192 / 64) * (8192 / 64) / 4, 256, 0, stream>>>(
        zb, zb, out, 8192, 8192, 128);
}